// Round 13
// baseline (62.549 us; speedup 1.0000x reference)
//
#include <hip/hip_runtime.h>

// KNN (k=16) within batch-diagonal blocks + neighbor-feature mean-pool.
// N = 16384 points, 8 batches of 2048 (contiguous), FEAT = 16.
//
// R12 -> R13: revert to R11's proven structure (41.7us, zero spill, zero
// bank conflicts) with one knob: REGC 16 -> 24 (cache 24 of 32 per-lane d2
// in registers; recompute only 8). Steady-state regs ~40 <= 64 cap; the
// uncached loop keeps its unroll-4 load window, so the R12 failure mode
// (full-unroll load hoisting -> pressure blowup -> array spill) can't recur.
//
// Exactness machinery unchanged (11 passing rounds): reference-bit d2
// (FMA chain, rounded squares, (x2+y2)-2*dot), thr = 16th-smallest of the
// 64 lane-mins (>=16 distinct candidates <= thr => provably valid), u64
// (mono(d2)<<32|idx) keys == lax.top_k stable order, ballot-compacted
// append, wave bitonic sort for final ranks, butterfly mean (rounding-only
// relaxation, ~1e-6 << 2.2e-2 threshold).

typedef unsigned long long u64;
typedef unsigned int u32;

#define FEAT 16
#define BLK_WAVES 8
#define THREADS (BLK_WAVES * 64)   // 512
#define LIST_CAP 512
#define INF_KEY 0xFFFFFFFFFFFFFFFFull

__global__ void knn_prep(const float* __restrict__ y, float4* __restrict__ yp, int m)
{
    const int j = blockIdx.x * 256 + (int)threadIdx.x;
    if (j < m) {
        const float a0 = y[(size_t)j * 3 + 0];
        const float a1 = y[(size_t)j * 3 + 1];
        const float a2 = y[(size_t)j * 3 + 2];
        const float s  = __fadd_rn(__fadd_rn(__fmul_rn(a0, a0), __fmul_rn(a1, a1)),
                                   __fmul_rn(a2, a2));
        yp[j] = make_float4(a0, a1, a2, s);
    }
}

__device__ __forceinline__ u32 mono(float f) {
    const u32 b = __float_as_uint(f);
    return b ^ (((u32)(((int)b) >> 31)) | 0x80000000u);
}
__device__ __forceinline__ float unmono(u32 h) {
    const u32 b = (h & 0x80000000u) ? (h & 0x7FFFFFFFu) : ~h;
    return __uint_as_float(b);
}
__device__ __forceinline__ int lanes_below(u64 mask) {
    return __builtin_amdgcn_mbcnt_hi((u32)(mask >> 32),
           __builtin_amdgcn_mbcnt_lo((u32)mask, 0));
}

// Cross-lane bitonic sort over the 64 lanes, ascending by lane index.
__device__ __forceinline__ u32 sort64_u32(u32 k, int lane) {
#pragma unroll
    for (int kk = 2; kk <= 64; kk <<= 1) {
#pragma unroll
        for (int j = kk >> 1; j > 0; j >>= 1) {
            const u32 o = __shfl_xor(k, j);
            const bool keep_min = (((lane & j) == 0) == ((lane & kk) == 0));
            const u32 mn = (k < o) ? k : o;
            const u32 mx = (k < o) ? o : k;
            k = keep_min ? mn : mx;
        }
    }
    return k;
}
__device__ __forceinline__ u64 sort64_u64(u64 k, int lane) {
#pragma unroll
    for (int kk = 2; kk <= 64; kk <<= 1) {
#pragma unroll
        for (int j = kk >> 1; j > 0; j >>= 1) {
            const u64 o = __shfl_xor(k, j);
            const bool keep_min = (((lane & j) == 0) == ((lane & kk) == 0));
            const u64 mn = (k < o) ? k : o;
            const u64 mx = (k < o) ? o : k;
            k = keep_min ? mn : mx;
        }
    }
    return k;
}

// REGC: leading iterations with register-cached d2. TOTC > 0: compile-time
// per-lane candidate count (packed fast path). TOTC == 0: runtime fallback.
template <int TOTC, int REGC>
__global__ __launch_bounds__(THREADS, 7) void knn_main(
    const float* __restrict__ x, const float4* __restrict__ yp,
    const float* __restrict__ y, const float* __restrict__ feat,
    const int* __restrict__ x_batch, float* __restrict__ out,
    int n, int per, int packed)
{
    __shared__ u64 list_s[BLK_WAVES][LIST_CAP];  // 32 KiB survivor lists

    const int lane = (int)threadIdx.x & 63;
    const int wv   = (int)(threadIdx.x >> 6);
    const int i    = blockIdx.x * BLK_WAVES + wv;   // this wave's point
    if (i >= n) return;

    const int b     = x_batch[i];                   // lane-uniform
    const int ybase = b * per;

    const float px0 = x[(size_t)i * 3 + 0];
    const float px1 = x[(size_t)i * 3 + 1];
    const float px2 = x[(size_t)i * 3 + 2];
    const float x2s = __fadd_rn(__fadd_rn(__fmul_rn(px0, px0), __fmul_rn(px1, px1)),
                                __fmul_rn(px2, px2));

    float thrf;
    int S = 0;                                      // wave-uniform count

    if constexpr (TOTC > 0) {
        // ---- Phase A: d2 over candidates j = ybase + t*64 + lane.
        float d2c[REGC];
        float md0 = __builtin_inff(), md1 = __builtin_inff();
#pragma unroll 4
        for (int t = 0; t < REGC; ++t) {
            const float4 q = yp[ybase + t * 64 + lane];   // coalesced
            float dot = __fmaf_rn(px0, q.x, 0.0f);
            dot = __fmaf_rn(px1, q.y, dot);
            dot = __fmaf_rn(px2, q.z, dot);
            const float d2 = __fsub_rn(__fadd_rn(x2s, q.w), __fmul_rn(2.0f, dot));
            d2c[t] = d2;
            if (t & 1) md1 = fminf(md1, d2); else md0 = fminf(md0, d2);
        }
#pragma unroll 4
        for (int t = REGC; t < TOTC; ++t) {
            const float4 q = yp[ybase + t * 64 + lane];
            float dot = __fmaf_rn(px0, q.x, 0.0f);
            dot = __fmaf_rn(px1, q.y, dot);
            dot = __fmaf_rn(px2, q.z, dot);
            const float d2 = __fsub_rn(__fadd_rn(x2s, q.w), __fmul_rn(2.0f, dot));
            if (t & 1) md1 = fminf(md1, d2); else md0 = fminf(md0, d2);
        }
        const float md = fminf(md0, md1);

        // thr = 16th-smallest of the 64 lane-mins (exact d2 bits).
        const u32 sorted = sort64_u32(mono(md), lane);
        thrf = unmono(__shfl(sorted, 15));

        // ---- Phase B: ballot-compacted append (no atomics).
#pragma unroll
        for (int t = 0; t < REGC; ++t) {
            const bool pred = (d2c[t] <= thrf);
            const u64 mask = __ballot(pred);
            if (pred) {
                const int slot = S + lanes_below(mask);
                if (slot < LIST_CAP)
                    list_s[wv][slot] =
                        ((u64)mono(d2c[t]) << 32) | (u32)(ybase + t * 64 + lane);
            }
            S += __popcll(mask);
        }
#pragma unroll 4
        for (int t = REGC; t < TOTC; ++t) {
            const float4 q = yp[ybase + t * 64 + lane];
            float dot = __fmaf_rn(px0, q.x, 0.0f);
            dot = __fmaf_rn(px1, q.y, dot);
            dot = __fmaf_rn(px2, q.z, dot);
            const float d2 = __fsub_rn(__fadd_rn(x2s, q.w), __fmul_rn(2.0f, dot));
            const bool pred = (d2 <= thrf);
            const u64 mask = __ballot(pred);
            if (pred) {
                const int slot = S + lanes_below(mask);
                if (slot < LIST_CAP)
                    list_s[wv][slot] =
                        ((u64)mono(d2) << 32) | (u32)(ybase + t * 64 + lane);
            }
            S += __popcll(mask);
        }
    } else {
        // Generic fallback: two-pass scan (R8 structure, unpacked y ok).
        const int iters = per / 64;
        float md = __builtin_inff();
        for (int t = 0; t < iters; ++t) {
            const int j = ybase + t * 64 + lane;
            float q0, q1, q2, qs;
            if (packed) {
                const float4 q = yp[j];
                q0 = q.x; q1 = q.y; q2 = q.z; qs = q.w;
            } else {
                q0 = y[(size_t)j * 3 + 0];
                q1 = y[(size_t)j * 3 + 1];
                q2 = y[(size_t)j * 3 + 2];
                qs = __fadd_rn(__fadd_rn(__fmul_rn(q0, q0), __fmul_rn(q1, q1)),
                               __fmul_rn(q2, q2));
            }
            float dot = __fmaf_rn(px0, q0, 0.0f);
            dot = __fmaf_rn(px1, q1, dot);
            dot = __fmaf_rn(px2, q2, dot);
            md = fminf(md, __fsub_rn(__fadd_rn(x2s, qs), __fmul_rn(2.0f, dot)));
        }
        const u32 sorted = sort64_u32(mono(md), lane);
        thrf = unmono(__shfl(sorted, 15));
        for (int t = 0; t < iters; ++t) {
            const int j = ybase + t * 64 + lane;
            float q0, q1, q2, qs;
            if (packed) {
                const float4 q = yp[j];
                q0 = q.x; q1 = q.y; q2 = q.z; qs = q.w;
            } else {
                q0 = y[(size_t)j * 3 + 0];
                q1 = y[(size_t)j * 3 + 1];
                q2 = y[(size_t)j * 3 + 2];
                qs = __fadd_rn(__fadd_rn(__fmul_rn(q0, q0), __fmul_rn(q1, q1)),
                               __fmul_rn(q2, q2));
            }
            float dot = __fmaf_rn(px0, q0, 0.0f);
            dot = __fmaf_rn(px1, q1, dot);
            dot = __fmaf_rn(px2, q2, dot);
            const float d2 = __fsub_rn(__fadd_rn(x2s, qs), __fmul_rn(2.0f, dot));
            const bool pred = (d2 <= thrf);
            const u64 mask = __ballot(pred);
            if (pred) {
                const int slot = S + lanes_below(mask);
                if (slot < LIST_CAP)
                    list_s[wv][slot] = ((u64)mono(d2) << 32) | (u32)j;
            }
            S += __popcll(mask);
        }
    }

    if (S > LIST_CAP) S = LIST_CAP;

    // ---- Phase C: top-16 via wave sort-64 (chunked for S > 64; exact).
    u64 k0 = (lane < S) ? list_s[wv][lane] : INF_KEY;
    u64 top = sort64_u64(k0, lane);
    for (int pos = 64; pos < S; pos += 48) {
        const int src = pos + lane - 16;
        const u64 k = (lane < 16) ? top
                                  : ((src < S) ? list_s[wv][src] : INF_KEY);
        top = sort64_u64(k, lane);
    }

    // ---- Gather + mean, all 64 lanes: rank = lane&15, chunk = lane>>4.
    const int r = lane & 15;
    const int c = lane >> 4;
    const u64 krank = __shfl(top, r);               // rank-r key (lanes 0..15)
    const int gidx  = (int)(u32)krank;              // global y index
    const float4 fq = ((const float4*)feat)[(size_t)gidx * 4 + c];
    float f0 = fq.x, f1 = fq.y, f2 = fq.z, f3 = fq.w;
#pragma unroll
    for (int mask = 1; mask <= 8; mask <<= 1) {     // sum over ranks in-group
        f0 = __fadd_rn(f0, __shfl_xor(f0, mask));
        f1 = __fadd_rn(f1, __shfl_xor(f1, mask));
        f2 = __fadd_rn(f2, __shfl_xor(f2, mask));
        f3 = __fadd_rn(f3, __shfl_xor(f3, mask));
    }
    if (r == 0) {
        float4* o4 = (float4*)out + (size_t)i * 4;
        o4[c] = make_float4(__fmul_rn(f0, 0.0625f), __fmul_rn(f1, 0.0625f),
                            __fmul_rn(f2, 0.0625f), __fmul_rn(f3, 0.0625f));
    }
}

extern "C" void kernel_launch(void* const* d_in, const int* in_sizes, int n_in,
                              void* d_out, int out_size, void* d_ws, size_t ws_size,
                              hipStream_t stream) {
    const float* x       = (const float*)d_in[0];
    const float* y       = (const float*)d_in[1];
    const float* feat    = (const float*)d_in[2];
    const int*   x_batch = (const int*)d_in[3];

    const int n   = in_sizes[0] / 3;   // 16384 query points
    const int m   = in_sizes[1] / 3;   // 16384 y points
    const int per = m / 8;             // 2048 per batch (N_BATCHES = 8)

    float* out = (float*)d_out;

    const size_t need = (size_t)m * sizeof(float4);
    const int packed = (ws_size >= need) ? 1 : 0;
    float4* yp = (float4*)d_ws;

    if (packed)
        knn_prep<<<(m + 255) / 256, 256, 0, stream>>>(y, yp, m);

    const int blocks = (n + BLK_WAVES - 1) / BLK_WAVES;   // 2048
    if (packed && per == 2048)
        knn_main<32, 24><<<blocks, THREADS, 0, stream>>>(x, yp, y, feat,
                                                         x_batch, out, n, per, packed);
    else
        knn_main<0, 0><<<blocks, THREADS, 0, stream>>>(x, yp, y, feat,
                                                       x_batch, out, n, per, packed);
}

// Round 14
// 53.013 us; speedup vs baseline: 1.1799x; 1.1799x over previous
//
#include <hip/hip_runtime.h>

// KNN (k=16) within batch-diagonal blocks + neighbor-feature mean-pool.
// N = 16384 points, 8 batches of 2048 (contiguous), FEAT = 16.
//
// R13 -> R14: R13's regression was self-inflicted: cached loop used
// "#pragma unroll 4" -> d2c runtime-indexed -> scratch (rule #20; VGPR 20,
// WRITE 99MB). R14 = R11's proven structure (41.7us, VGPR 32, zero spill)
// with REGC 16 -> 24 done RIGHT: full static unroll on both cached loops;
// uncached tail (8 iters) keeps the unroll-4 runtime form (touches no
// arrays). Expected ~40-48 VGPR, no spill.
//
// Exactness machinery unchanged (12 passing rounds): reference-bit d2
// (ascending-k FMA chain, rounded squares, (x2+y2)-2*dot), thr =
// 16th-smallest of the 64 lane-mins (>=16 distinct candidates <= thr =>
// provably valid), u64 (mono(d2)<<32|idx) keys == lax.top_k stable order,
// ballot-compacted append, wave bitonic sort-64 for final ranks, butterfly
// mean (rounding-only relaxation, ~1e-6 << 2.2e-2 threshold).

typedef unsigned long long u64;
typedef unsigned int u32;

#define FEAT 16
#define BLK_WAVES 8
#define THREADS (BLK_WAVES * 64)   // 512
#define LIST_CAP 512
#define INF_KEY 0xFFFFFFFFFFFFFFFFull

__global__ void knn_prep(const float* __restrict__ y, float4* __restrict__ yp, int m)
{
    const int j = blockIdx.x * 256 + (int)threadIdx.x;
    if (j < m) {
        const float a0 = y[(size_t)j * 3 + 0];
        const float a1 = y[(size_t)j * 3 + 1];
        const float a2 = y[(size_t)j * 3 + 2];
        const float s  = __fadd_rn(__fadd_rn(__fmul_rn(a0, a0), __fmul_rn(a1, a1)),
                                   __fmul_rn(a2, a2));
        yp[j] = make_float4(a0, a1, a2, s);
    }
}

__device__ __forceinline__ u32 mono(float f) {
    const u32 b = __float_as_uint(f);
    return b ^ (((u32)(((int)b) >> 31)) | 0x80000000u);
}
__device__ __forceinline__ float unmono(u32 h) {
    const u32 b = (h & 0x80000000u) ? (h & 0x7FFFFFFFu) : ~h;
    return __uint_as_float(b);
}
__device__ __forceinline__ int lanes_below(u64 mask) {
    return __builtin_amdgcn_mbcnt_hi((u32)(mask >> 32),
           __builtin_amdgcn_mbcnt_lo((u32)mask, 0));
}

// Cross-lane bitonic sort over the 64 lanes, ascending by lane index.
__device__ __forceinline__ u32 sort64_u32(u32 k, int lane) {
#pragma unroll
    for (int kk = 2; kk <= 64; kk <<= 1) {
#pragma unroll
        for (int j = kk >> 1; j > 0; j >>= 1) {
            const u32 o = __shfl_xor(k, j);
            const bool keep_min = (((lane & j) == 0) == ((lane & kk) == 0));
            const u32 mn = (k < o) ? k : o;
            const u32 mx = (k < o) ? o : k;
            k = keep_min ? mn : mx;
        }
    }
    return k;
}
__device__ __forceinline__ u64 sort64_u64(u64 k, int lane) {
#pragma unroll
    for (int kk = 2; kk <= 64; kk <<= 1) {
#pragma unroll
        for (int j = kk >> 1; j > 0; j >>= 1) {
            const u64 o = __shfl_xor(k, j);
            const bool keep_min = (((lane & j) == 0) == ((lane & kk) == 0));
            const u64 mn = (k < o) ? k : o;
            const u64 mx = (k < o) ? o : k;
            k = keep_min ? mn : mx;
        }
    }
    return k;
}

// REGC: leading iterations with register-cached d2 (FULL static unroll).
// TOTC > 0: compile-time per-lane candidate count. TOTC == 0: fallback.
template <int TOTC, int REGC>
__global__ __launch_bounds__(THREADS, 7) void knn_main(
    const float* __restrict__ x, const float4* __restrict__ yp,
    const float* __restrict__ y, const float* __restrict__ feat,
    const int* __restrict__ x_batch, float* __restrict__ out,
    int n, int per, int packed)
{
    __shared__ u64 list_s[BLK_WAVES][LIST_CAP];  // 32 KiB survivor lists

    const int lane = (int)threadIdx.x & 63;
    const int wv   = (int)(threadIdx.x >> 6);
    const int i    = blockIdx.x * BLK_WAVES + wv;   // this wave's point
    if (i >= n) return;

    const int b     = x_batch[i];                   // lane-uniform
    const int ybase = b * per;

    const float px0 = x[(size_t)i * 3 + 0];
    const float px1 = x[(size_t)i * 3 + 1];
    const float px2 = x[(size_t)i * 3 + 2];
    const float x2s = __fadd_rn(__fadd_rn(__fmul_rn(px0, px0), __fmul_rn(px1, px1)),
                                __fmul_rn(px2, px2));

    float thrf;
    int S = 0;                                      // wave-uniform count

    if constexpr (TOTC > 0) {
        // ---- Phase A: d2 over candidates j = ybase + t*64 + lane.
        // Cached loop: FULL unroll (static indexing -> registers; rule #20).
        float d2c[REGC];
        float md0 = __builtin_inff(), md1 = __builtin_inff();
#pragma unroll
        for (int t = 0; t < REGC; ++t) {
            const float4 q = yp[ybase + t * 64 + lane];   // coalesced
            float dot = __fmaf_rn(px0, q.x, 0.0f);
            dot = __fmaf_rn(px1, q.y, dot);
            dot = __fmaf_rn(px2, q.z, dot);
            const float d2 = __fsub_rn(__fadd_rn(x2s, q.w), __fmul_rn(2.0f, dot));
            d2c[t] = d2;
            if (t & 1) md1 = fminf(md1, d2); else md0 = fminf(md0, d2);
        }
#pragma unroll 4
        for (int t = REGC; t < TOTC; ++t) {
            const float4 q = yp[ybase + t * 64 + lane];
            float dot = __fmaf_rn(px0, q.x, 0.0f);
            dot = __fmaf_rn(px1, q.y, dot);
            dot = __fmaf_rn(px2, q.z, dot);
            const float d2 = __fsub_rn(__fadd_rn(x2s, q.w), __fmul_rn(2.0f, dot));
            if (t & 1) md1 = fminf(md1, d2); else md0 = fminf(md0, d2);
        }
        const float md = fminf(md0, md1);

        // thr = 16th-smallest of the 64 lane-mins (exact d2 bits).
        const u32 sorted = sort64_u32(mono(md), lane);
        thrf = unmono(__shfl(sorted, 15));

        // ---- Phase B: ballot-compacted append (no atomics).
#pragma unroll
        for (int t = 0; t < REGC; ++t) {
            const bool pred = (d2c[t] <= thrf);
            const u64 mask = __ballot(pred);
            if (pred) {
                const int slot = S + lanes_below(mask);
                if (slot < LIST_CAP)
                    list_s[wv][slot] =
                        ((u64)mono(d2c[t]) << 32) | (u32)(ybase + t * 64 + lane);
            }
            S += __popcll(mask);
        }
#pragma unroll 4
        for (int t = REGC; t < TOTC; ++t) {
            const float4 q = yp[ybase + t * 64 + lane];
            float dot = __fmaf_rn(px0, q.x, 0.0f);
            dot = __fmaf_rn(px1, q.y, dot);
            dot = __fmaf_rn(px2, q.z, dot);
            const float d2 = __fsub_rn(__fadd_rn(x2s, q.w), __fmul_rn(2.0f, dot));
            const bool pred = (d2 <= thrf);
            const u64 mask = __ballot(pred);
            if (pred) {
                const int slot = S + lanes_below(mask);
                if (slot < LIST_CAP)
                    list_s[wv][slot] =
                        ((u64)mono(d2) << 32) | (u32)(ybase + t * 64 + lane);
            }
            S += __popcll(mask);
        }
    } else {
        // Generic fallback: two-pass scan (R8 structure, unpacked y ok).
        const int iters = per / 64;
        float md = __builtin_inff();
        for (int t = 0; t < iters; ++t) {
            const int j = ybase + t * 64 + lane;
            float q0, q1, q2, qs;
            if (packed) {
                const float4 q = yp[j];
                q0 = q.x; q1 = q.y; q2 = q.z; qs = q.w;
            } else {
                q0 = y[(size_t)j * 3 + 0];
                q1 = y[(size_t)j * 3 + 1];
                q2 = y[(size_t)j * 3 + 2];
                qs = __fadd_rn(__fadd_rn(__fmul_rn(q0, q0), __fmul_rn(q1, q1)),
                               __fmul_rn(q2, q2));
            }
            float dot = __fmaf_rn(px0, q0, 0.0f);
            dot = __fmaf_rn(px1, q1, dot);
            dot = __fmaf_rn(px2, q2, dot);
            md = fminf(md, __fsub_rn(__fadd_rn(x2s, qs), __fmul_rn(2.0f, dot)));
        }
        const u32 sorted = sort64_u32(mono(md), lane);
        thrf = unmono(__shfl(sorted, 15));
        for (int t = 0; t < iters; ++t) {
            const int j = ybase + t * 64 + lane;
            float q0, q1, q2, qs;
            if (packed) {
                const float4 q = yp[j];
                q0 = q.x; q1 = q.y; q2 = q.z; qs = q.w;
            } else {
                q0 = y[(size_t)j * 3 + 0];
                q1 = y[(size_t)j * 3 + 1];
                q2 = y[(size_t)j * 3 + 2];
                qs = __fadd_rn(__fadd_rn(__fmul_rn(q0, q0), __fmul_rn(q1, q1)),
                               __fmul_rn(q2, q2));
            }
            float dot = __fmaf_rn(px0, q0, 0.0f);
            dot = __fmaf_rn(px1, q1, dot);
            dot = __fmaf_rn(px2, q2, dot);
            const float d2 = __fsub_rn(__fadd_rn(x2s, qs), __fmul_rn(2.0f, dot));
            const bool pred = (d2 <= thrf);
            const u64 mask = __ballot(pred);
            if (pred) {
                const int slot = S + lanes_below(mask);
                if (slot < LIST_CAP)
                    list_s[wv][slot] = ((u64)mono(d2) << 32) | (u32)j;
            }
            S += __popcll(mask);
        }
    }

    if (S > LIST_CAP) S = LIST_CAP;

    // ---- Phase C: top-16 via wave sort-64 (chunked for S > 64; exact).
    u64 k0 = (lane < S) ? list_s[wv][lane] : INF_KEY;
    u64 top = sort64_u64(k0, lane);
    for (int pos = 64; pos < S; pos += 48) {
        const int src = pos + lane - 16;
        const u64 k = (lane < 16) ? top
                                  : ((src < S) ? list_s[wv][src] : INF_KEY);
        top = sort64_u64(k, lane);
    }

    // ---- Gather + mean, all 64 lanes: rank = lane&15, chunk = lane>>4.
    const int r = lane & 15;
    const int c = lane >> 4;
    const u64 krank = __shfl(top, r);               // rank-r key (lanes 0..15)
    const int gidx  = (int)(u32)krank;              // global y index
    const float4 fq = ((const float4*)feat)[(size_t)gidx * 4 + c];
    float f0 = fq.x, f1 = fq.y, f2 = fq.z, f3 = fq.w;
#pragma unroll
    for (int mask = 1; mask <= 8; mask <<= 1) {     // sum over ranks in-group
        f0 = __fadd_rn(f0, __shfl_xor(f0, mask));
        f1 = __fadd_rn(f1, __shfl_xor(f1, mask));
        f2 = __fadd_rn(f2, __shfl_xor(f2, mask));
        f3 = __fadd_rn(f3, __shfl_xor(f3, mask));
    }
    if (r == 0) {
        float4* o4 = (float4*)out + (size_t)i * 4;
        o4[c] = make_float4(__fmul_rn(f0, 0.0625f), __fmul_rn(f1, 0.0625f),
                            __fmul_rn(f2, 0.0625f), __fmul_rn(f3, 0.0625f));
    }
}

extern "C" void kernel_launch(void* const* d_in, const int* in_sizes, int n_in,
                              void* d_out, int out_size, void* d_ws, size_t ws_size,
                              hipStream_t stream) {
    const float* x       = (const float*)d_in[0];
    const float* y       = (const float*)d_in[1];
    const float* feat    = (const float*)d_in[2];
    const int*   x_batch = (const int*)d_in[3];

    const int n   = in_sizes[0] / 3;   // 16384 query points
    const int m   = in_sizes[1] / 3;   // 16384 y points
    const int per = m / 8;             // 2048 per batch (N_BATCHES = 8)

    float* out = (float*)d_out;

    const size_t need = (size_t)m * sizeof(float4);
    const int packed = (ws_size >= need) ? 1 : 0;
    float4* yp = (float4*)d_ws;

    if (packed)
        knn_prep<<<(m + 255) / 256, 256, 0, stream>>>(y, yp, m);

    const int blocks = (n + BLK_WAVES - 1) / BLK_WAVES;   // 2048
    if (packed && per == 2048)
        knn_main<32, 24><<<blocks, THREADS, 0, stream>>>(x, yp, y, feat,
                                                         x_batch, out, n, per, packed);
    else
        knn_main<0, 0><<<blocks, THREADS, 0, stream>>>(x, yp, y, feat,
                                                       x_batch, out, n, per, packed);
}

// Round 15
// 41.594 us; speedup vs baseline: 1.5038x; 1.2745x over previous
//
#include <hip/hip_runtime.h>

// KNN (k=16) within batch-diagonal blocks + neighbor-feature mean-pool.
// N = 16384 points, 8 batches of 2048 (contiguous), FEAT = 16.
//
// R15 = R11 restored verbatim (measured best: 41.7us, VGPR 32, zero spill,
// zero bank conflicts). The REGC knob is exhausted by measurement:
//   REGC=16 full-unroll (R11): 41.7us  <- optimum
//   REGC=32 full-unroll (R12): 55.2us  (load-hoist pressure -> spill)
//   REGC=24 unroll-4    (R13): 62.5us  (runtime-indexed array -> scratch)
//   REGC=24 full-unroll (R14): 53.0us  (fits, but load pipeline serializes)
//
// Structure: one wave = one point. Phase A: 32 coalesced float4 loads,
// d2 for 16 cached in regs + 16 recomputed later; thr = 16th-smallest of
// the 64 lane-mins (wave bitonic sort-64 on mono keys; >= 16 distinct
// candidates <= thr => provably valid). Phase B: ballot-compacted append
// of survivors (E[S]~18) to a per-wave LDS list. Phase C: wave bitonic
// sort-64 of u64 (mono(d2)<<32|idx) keys == lax.top_k stable order (exact
// selection; chunked loop covers S>64). Gather: all 64 lanes, butterfly
// mean over ranks (rounding-only relaxation, ~1e-6 << 2.2e-2 threshold).
// Distance arithmetic = reference bits: ascending-k FMA chain, rounded
// squares + sequential adds, (x2+y2) - 2*dot, all __f*_rn.

typedef unsigned long long u64;
typedef unsigned int u32;

#define FEAT 16
#define BLK_WAVES 8
#define THREADS (BLK_WAVES * 64)   // 512
#define LIST_CAP 512
#define INF_KEY 0xFFFFFFFFFFFFFFFFull

__global__ void knn_prep(const float* __restrict__ y, float4* __restrict__ yp, int m)
{
    const int j = blockIdx.x * 256 + (int)threadIdx.x;
    if (j < m) {
        const float a0 = y[(size_t)j * 3 + 0];
        const float a1 = y[(size_t)j * 3 + 1];
        const float a2 = y[(size_t)j * 3 + 2];
        const float s  = __fadd_rn(__fadd_rn(__fmul_rn(a0, a0), __fmul_rn(a1, a1)),
                                   __fmul_rn(a2, a2));
        yp[j] = make_float4(a0, a1, a2, s);
    }
}

__device__ __forceinline__ u32 mono(float f) {
    const u32 b = __float_as_uint(f);
    return b ^ (((u32)(((int)b) >> 31)) | 0x80000000u);
}
__device__ __forceinline__ float unmono(u32 h) {
    const u32 b = (h & 0x80000000u) ? (h & 0x7FFFFFFFu) : ~h;
    return __uint_as_float(b);
}
__device__ __forceinline__ int lanes_below(u64 mask) {
    return __builtin_amdgcn_mbcnt_hi((u32)(mask >> 32),
           __builtin_amdgcn_mbcnt_lo((u32)mask, 0));
}

// Cross-lane bitonic sort over the 64 lanes, ascending by lane index.
__device__ __forceinline__ u32 sort64_u32(u32 k, int lane) {
#pragma unroll
    for (int kk = 2; kk <= 64; kk <<= 1) {
#pragma unroll
        for (int j = kk >> 1; j > 0; j >>= 1) {
            const u32 o = __shfl_xor(k, j);
            const bool keep_min = (((lane & j) == 0) == ((lane & kk) == 0));
            const u32 mn = (k < o) ? k : o;
            const u32 mx = (k < o) ? o : k;
            k = keep_min ? mn : mx;
        }
    }
    return k;
}
__device__ __forceinline__ u64 sort64_u64(u64 k, int lane) {
#pragma unroll
    for (int kk = 2; kk <= 64; kk <<= 1) {
#pragma unroll
        for (int j = kk >> 1; j > 0; j >>= 1) {
            const u64 o = __shfl_xor(k, j);
            const bool keep_min = (((lane & j) == 0) == ((lane & kk) == 0));
            const u64 mn = (k < o) ? k : o;
            const u64 mx = (k < o) ? o : k;
            k = keep_min ? mn : mx;
        }
    }
    return k;
}

// REGC: leading iterations with register-cached d2 (FULL static unroll).
// TOTC > 0: compile-time per-lane candidate count. TOTC == 0: fallback.
template <int TOTC, int REGC>
__global__ __launch_bounds__(THREADS, 7) void knn_main(
    const float* __restrict__ x, const float4* __restrict__ yp,
    const float* __restrict__ y, const float* __restrict__ feat,
    const int* __restrict__ x_batch, float* __restrict__ out,
    int n, int per, int packed)
{
    __shared__ u64 list_s[BLK_WAVES][LIST_CAP];  // 32 KiB survivor lists

    const int lane = (int)threadIdx.x & 63;
    const int wv   = (int)(threadIdx.x >> 6);
    const int i    = blockIdx.x * BLK_WAVES + wv;   // this wave's point
    if (i >= n) return;

    const int b     = x_batch[i];                   // lane-uniform
    const int ybase = b * per;

    const float px0 = x[(size_t)i * 3 + 0];
    const float px1 = x[(size_t)i * 3 + 1];
    const float px2 = x[(size_t)i * 3 + 2];
    const float x2s = __fadd_rn(__fadd_rn(__fmul_rn(px0, px0), __fmul_rn(px1, px1)),
                                __fmul_rn(px2, px2));

    float thrf;
    int S = 0;                                      // wave-uniform count

    if constexpr (TOTC > 0) {
        // ---- Phase A: d2 over candidates j = ybase + t*64 + lane.
        float d2c[REGC];
        float md0 = __builtin_inff(), md1 = __builtin_inff();
#pragma unroll
        for (int t = 0; t < REGC; ++t) {
            const float4 q = yp[ybase + t * 64 + lane];   // coalesced
            float dot = __fmaf_rn(px0, q.x, 0.0f);
            dot = __fmaf_rn(px1, q.y, dot);
            dot = __fmaf_rn(px2, q.z, dot);
            const float d2 = __fsub_rn(__fadd_rn(x2s, q.w), __fmul_rn(2.0f, dot));
            d2c[t] = d2;
            if (t & 1) md1 = fminf(md1, d2); else md0 = fminf(md0, d2);
        }
#pragma unroll 4
        for (int t = REGC; t < TOTC; ++t) {
            const float4 q = yp[ybase + t * 64 + lane];
            float dot = __fmaf_rn(px0, q.x, 0.0f);
            dot = __fmaf_rn(px1, q.y, dot);
            dot = __fmaf_rn(px2, q.z, dot);
            const float d2 = __fsub_rn(__fadd_rn(x2s, q.w), __fmul_rn(2.0f, dot));
            if (t & 1) md1 = fminf(md1, d2); else md0 = fminf(md0, d2);
        }
        const float md = fminf(md0, md1);

        // thr = 16th-smallest of the 64 lane-mins (exact d2 bits).
        const u32 sorted = sort64_u32(mono(md), lane);
        thrf = unmono(__shfl(sorted, 15));

        // ---- Phase B: ballot-compacted append (no atomics).
#pragma unroll
        for (int t = 0; t < REGC; ++t) {
            const bool pred = (d2c[t] <= thrf);
            const u64 mask = __ballot(pred);
            if (pred) {
                const int slot = S + lanes_below(mask);
                if (slot < LIST_CAP)
                    list_s[wv][slot] =
                        ((u64)mono(d2c[t]) << 32) | (u32)(ybase + t * 64 + lane);
            }
            S += __popcll(mask);
        }
#pragma unroll 4
        for (int t = REGC; t < TOTC; ++t) {
            const float4 q = yp[ybase + t * 64 + lane];
            float dot = __fmaf_rn(px0, q.x, 0.0f);
            dot = __fmaf_rn(px1, q.y, dot);
            dot = __fmaf_rn(px2, q.z, dot);
            const float d2 = __fsub_rn(__fadd_rn(x2s, q.w), __fmul_rn(2.0f, dot));
            const bool pred = (d2 <= thrf);
            const u64 mask = __ballot(pred);
            if (pred) {
                const int slot = S + lanes_below(mask);
                if (slot < LIST_CAP)
                    list_s[wv][slot] =
                        ((u64)mono(d2) << 32) | (u32)(ybase + t * 64 + lane);
            }
            S += __popcll(mask);
        }
    } else {
        // Generic fallback: two-pass scan (R8 structure, unpacked y ok).
        const int iters = per / 64;
        float md = __builtin_inff();
        for (int t = 0; t < iters; ++t) {
            const int j = ybase + t * 64 + lane;
            float q0, q1, q2, qs;
            if (packed) {
                const float4 q = yp[j];
                q0 = q.x; q1 = q.y; q2 = q.z; qs = q.w;
            } else {
                q0 = y[(size_t)j * 3 + 0];
                q1 = y[(size_t)j * 3 + 1];
                q2 = y[(size_t)j * 3 + 2];
                qs = __fadd_rn(__fadd_rn(__fmul_rn(q0, q0), __fmul_rn(q1, q1)),
                               __fmul_rn(q2, q2));
            }
            float dot = __fmaf_rn(px0, q0, 0.0f);
            dot = __fmaf_rn(px1, q1, dot);
            dot = __fmaf_rn(px2, q2, dot);
            md = fminf(md, __fsub_rn(__fadd_rn(x2s, qs), __fmul_rn(2.0f, dot)));
        }
        const u32 sorted = sort64_u32(mono(md), lane);
        thrf = unmono(__shfl(sorted, 15));
        for (int t = 0; t < iters; ++t) {
            const int j = ybase + t * 64 + lane;
            float q0, q1, q2, qs;
            if (packed) {
                const float4 q = yp[j];
                q0 = q.x; q1 = q.y; q2 = q.z; qs = q.w;
            } else {
                q0 = y[(size_t)j * 3 + 0];
                q1 = y[(size_t)j * 3 + 1];
                q2 = y[(size_t)j * 3 + 2];
                qs = __fadd_rn(__fadd_rn(__fmul_rn(q0, q0), __fmul_rn(q1, q1)),
                               __fmul_rn(q2, q2));
            }
            float dot = __fmaf_rn(px0, q0, 0.0f);
            dot = __fmaf_rn(px1, q1, dot);
            dot = __fmaf_rn(px2, q2, dot);
            const float d2 = __fsub_rn(__fadd_rn(x2s, qs), __fmul_rn(2.0f, dot));
            const bool pred = (d2 <= thrf);
            const u64 mask = __ballot(pred);
            if (pred) {
                const int slot = S + lanes_below(mask);
                if (slot < LIST_CAP)
                    list_s[wv][slot] = ((u64)mono(d2) << 32) | (u32)j;
            }
            S += __popcll(mask);
        }
    }

    if (S > LIST_CAP) S = LIST_CAP;

    // ---- Phase C: top-16 via wave sort-64 (chunked for S > 64; exact).
    u64 k0 = (lane < S) ? list_s[wv][lane] : INF_KEY;
    u64 top = sort64_u64(k0, lane);
    for (int pos = 64; pos < S; pos += 48) {
        const int src = pos + lane - 16;
        const u64 k = (lane < 16) ? top
                                  : ((src < S) ? list_s[wv][src] : INF_KEY);
        top = sort64_u64(k, lane);
    }

    // ---- Gather + mean, all 64 lanes: rank = lane&15, chunk = lane>>4.
    const int r = lane & 15;
    const int c = lane >> 4;
    const u64 krank = __shfl(top, r);               // rank-r key (lanes 0..15)
    const int gidx  = (int)(u32)krank;              // global y index
    const float4 fq = ((const float4*)feat)[(size_t)gidx * 4 + c];
    float f0 = fq.x, f1 = fq.y, f2 = fq.z, f3 = fq.w;
#pragma unroll
    for (int mask = 1; mask <= 8; mask <<= 1) {     // sum over ranks in-group
        f0 = __fadd_rn(f0, __shfl_xor(f0, mask));
        f1 = __fadd_rn(f1, __shfl_xor(f1, mask));
        f2 = __fadd_rn(f2, __shfl_xor(f2, mask));
        f3 = __fadd_rn(f3, __shfl_xor(f3, mask));
    }
    if (r == 0) {
        float4* o4 = (float4*)out + (size_t)i * 4;
        o4[c] = make_float4(__fmul_rn(f0, 0.0625f), __fmul_rn(f1, 0.0625f),
                            __fmul_rn(f2, 0.0625f), __fmul_rn(f3, 0.0625f));
    }
}

extern "C" void kernel_launch(void* const* d_in, const int* in_sizes, int n_in,
                              void* d_out, int out_size, void* d_ws, size_t ws_size,
                              hipStream_t stream) {
    const float* x       = (const float*)d_in[0];
    const float* y       = (const float*)d_in[1];
    const float* feat    = (const float*)d_in[2];
    const int*   x_batch = (const int*)d_in[3];

    const int n   = in_sizes[0] / 3;   // 16384 query points
    const int m   = in_sizes[1] / 3;   // 16384 y points
    const int per = m / 8;             // 2048 per batch (N_BATCHES = 8)

    float* out = (float*)d_out;

    const size_t need = (size_t)m * sizeof(float4);
    const int packed = (ws_size >= need) ? 1 : 0;
    float4* yp = (float4*)d_ws;

    if (packed)
        knn_prep<<<(m + 255) / 256, 256, 0, stream>>>(y, yp, m);

    const int blocks = (n + BLK_WAVES - 1) / BLK_WAVES;   // 2048
    if (packed && per == 2048)
        knn_main<32, 16><<<blocks, THREADS, 0, stream>>>(x, yp, y, feat,
                                                         x_batch, out, n, per, packed);
    else
        knn_main<0, 0><<<blocks, THREADS, 0, stream>>>(x, yp, y, feat,
                                                       x_batch, out, n, per, packed);
}